// Round 1
// baseline (388.634 us; speedup 1.0000x reference)
//
#include <hip/hip_runtime.h>
#include <hip/hip_bf16.h>
#include <math.h>

// Problem constants
#define DM 1024   // d_model
#define DS 16     // d_state
#define BB 4      // batch
#define LL 2048   // seq len
#define LC 64     // scan chunk length
#define NC (LL/LC) // 32 chunks

// ---------------- Kernel 1: dt = softplus(X @ W_dt^T + b_dt) ----------------
// f32 tiled GEMM, BM=BN=128, BK=32, 256 threads, 8x8 per thread.
#define BM 128
#define BN 128
#define BK 32

__global__ __launch_bounds__(256) void gemm_dt_kernel(
    const float* __restrict__ X, const float* __restrict__ W,
    const float* __restrict__ bias, float* __restrict__ DT)
{
  __shared__ float As[BK][BM + 4];  // [k][r], +4 pad keeps float4 alignment & banks spread
  __shared__ float Bs[BK][BN + 4];  // [k][e]
  const int tid  = threadIdx.x;
  const int row0 = blockIdx.y * BM;
  const int col0 = blockIdx.x * BN;
  const int lkx  = (tid & 7) * 4;   // k offset within tile (0,4,...,28)
  const int lky  = tid >> 3;        // row 0..31 (then +32*j)
  const int tx   = tid & 15, ty = tid >> 4;

  float acc[8][8];
#pragma unroll
  for (int i = 0; i < 8; ++i)
#pragma unroll
    for (int j = 0; j < 8; ++j) acc[i][j] = 0.f;

  for (int k0 = 0; k0 < DM; k0 += BK) {
#pragma unroll
    for (int j = 0; j < 4; ++j) {
      const int ra = row0 + lky + 32 * j;
      const int rb = col0 + lky + 32 * j;
      const float4 a = *(const float4*)&X[(size_t)ra * DM + k0 + lkx];
      const float4 b = *(const float4*)&W[(size_t)rb * DM + k0 + lkx];
      As[lkx + 0][lky + 32 * j] = a.x;
      As[lkx + 1][lky + 32 * j] = a.y;
      As[lkx + 2][lky + 32 * j] = a.z;
      As[lkx + 3][lky + 32 * j] = a.w;
      Bs[lkx + 0][lky + 32 * j] = b.x;
      Bs[lkx + 1][lky + 32 * j] = b.y;
      Bs[lkx + 2][lky + 32 * j] = b.z;
      Bs[lkx + 3][lky + 32 * j] = b.w;
    }
    __syncthreads();
#pragma unroll
    for (int kk = 0; kk < BK; ++kk) {
      const float4 a0 = *(const float4*)&As[kk][ty * 8];
      const float4 a1 = *(const float4*)&As[kk][ty * 8 + 4];
      const float4 b0 = *(const float4*)&Bs[kk][tx * 8];
      const float4 b1 = *(const float4*)&Bs[kk][tx * 8 + 4];
      const float ar[8] = {a0.x, a0.y, a0.z, a0.w, a1.x, a1.y, a1.z, a1.w};
      const float br[8] = {b0.x, b0.y, b0.z, b0.w, b1.x, b1.y, b1.z, b1.w};
#pragma unroll
      for (int i = 0; i < 8; ++i)
#pragma unroll
        for (int j = 0; j < 8; ++j)
          acc[i][j] = fmaf(ar[i], br[j], acc[i][j]);
    }
    __syncthreads();
  }

#pragma unroll
  for (int i = 0; i < 8; ++i) {
    const size_t r = (size_t)(row0 + ty * 8 + i);
#pragma unroll
    for (int j = 0; j < 8; ++j) {
      const int e = col0 + tx * 8 + j;
      const float v = acc[i][j] + bias[e];
      // stable softplus, matches jax.nn.softplus = max(v,0)+log1p(exp(-|v|))
      acc[i][j] = fmaxf(v, 0.f) + log1pf(__expf(-fabsf(v)));
    }
    *(float4*)&DT[r * DM + col0 + tx * 8] =
        make_float4(acc[i][0], acc[i][1], acc[i][2], acc[i][3]);
    *(float4*)&DT[r * DM + col0 + tx * 8 + 4] =
        make_float4(acc[i][4], acc[i][5], acc[i][6], acc[i][7]);
  }
}

// ---------------- Kernel 2: Bp/Cp = X @ {W_B,W_C}^T  (skinny) ----------------
// One wave per 2 rows; W loads amortized over 2 rows; butterfly reduce.
__global__ __launch_bounds__(256) void proj_bc_kernel(
    const float* __restrict__ X, const float* __restrict__ WB,
    const float* __restrict__ WC, float* __restrict__ Bp, float* __restrict__ Cp)
{
  const int lane = threadIdx.x & 63;
  const int wid  = (blockIdx.x * 256 + threadIdx.x) >> 6;  // 0..4095
  const size_t r0 = (size_t)wid * 2;
  float aB0[DS] = {}, aB1[DS] = {}, aC0[DS] = {}, aC1[DS] = {};

  for (int k = lane; k < DM; k += 64) {
    const float x0 = X[r0 * DM + k];
    const float x1 = X[(r0 + 1) * DM + k];
#pragma unroll
    for (int n = 0; n < DS; ++n) {
      const float wb = WB[n * DM + k];
      const float wc = WC[n * DM + k];
      aB0[n] = fmaf(x0, wb, aB0[n]);
      aB1[n] = fmaf(x1, wb, aB1[n]);
      aC0[n] = fmaf(x0, wc, aC0[n]);
      aC1[n] = fmaf(x1, wc, aC1[n]);
    }
  }
#pragma unroll
  for (int n = 0; n < DS; ++n) {
#pragma unroll
    for (int off = 32; off > 0; off >>= 1) {
      aB0[n] += __shfl_xor(aB0[n], off, 64);
      aB1[n] += __shfl_xor(aB1[n], off, 64);
      aC0[n] += __shfl_xor(aC0[n], off, 64);
      aC1[n] += __shfl_xor(aC1[n], off, 64);
    }
  }
  if (lane == 0) {
#pragma unroll
    for (int n = 0; n < DS; ++n) {
      Bp[r0 * DS + n]       = aB0[n];
      Bp[(r0 + 1) * DS + n] = aB1[n];
      Cp[r0 * DS + n]       = aC0[n];
      Cp[(r0 + 1) * DS + n] = aC1[n];
    }
  }
}

// ---------------- Kernel 3: per-chunk local scan (pass A) ----------------
// Thread = one d channel; chunk c; batch b. Stores chunk decay product P and
// local end-state h.
__global__ __launch_bounds__(256) void scan_partial_kernel(
    const float* __restrict__ DT, const float* __restrict__ X,
    const float* __restrict__ Bp, const float* __restrict__ A_log,
    float* __restrict__ PP, float* __restrict__ HP)
{
  const int d = blockIdx.x * 256 + threadIdx.x;
  const int c = blockIdx.y;
  const int b = blockIdx.z;
  float A[DS], h[DS], P[DS];
#pragma unroll
  for (int n = 0; n < DS; ++n) {
    A[n] = -__expf(A_log[d * DS + n]);
    h[n] = 0.f;
    P[n] = 1.f;
  }
  const int l0 = c * LC;
  size_t idx = ((size_t)b * LL + l0) * DM + d;
  const float* brow = &Bp[((size_t)b * LL + l0) * DS];
  float dtv = DT[idx], xv = X[idx];
  for (int l = 0; l < LC; ++l) {
    float ndt = 0.f, nx = 0.f;
    if (l + 1 < LC) { ndt = DT[idx + DM]; nx = X[idx + DM]; }  // prefetch
    const float dx = dtv * xv;
#pragma unroll
    for (int n = 0; n < DS; ++n) {
      const float dA = __expf(dtv * A[n]);
      P[n] *= dA;
      h[n] = fmaf(dA, h[n], dx * brow[n]);
    }
    brow += DS;
    idx += DM;
    dtv = ndt; xv = nx;
  }
  const size_t o = (((size_t)b * NC + c) * DM + d) * DS;
#pragma unroll
  for (int n = 0; n < DS; ++n) { PP[o + n] = P[n]; HP[o + n] = h[n]; }
}

// ---------------- Kernel 4: combine chunk prefixes (sequential over NC) -----
// In-place: PP becomes Hin (chunk-entry state). Reads P/HP before overwrite.
__global__ __launch_bounds__(256) void combine_kernel(
    float* __restrict__ PP, const float* __restrict__ HP)
{
  const int idx = blockIdx.x * 256 + threadIdx.x;  // over B*DM*DS = 65536
  const int b  = idx >> 14;
  const int dn = idx & 16383;
  float h = 0.f;
#pragma unroll
  for (int c = 0; c < NC; ++c) {
    const size_t o = (((size_t)b * NC + c) << 14) + dn;
    const float p  = PP[o];
    const float hp = HP[o];
    PP[o] = h;              // Hin for chunk c
    h = fmaf(p, h, hp);
  }
}

// ---------------- Kernel 5: final scan + output (pass B) ----------------
__global__ __launch_bounds__(256) void scan_final_kernel(
    const float* __restrict__ DT, const float* __restrict__ X,
    const float* __restrict__ Bp, const float* __restrict__ Cp,
    const float* __restrict__ A_log, const float* __restrict__ Dvec,
    const float* __restrict__ Hin, float* __restrict__ Y)
{
  const int d = blockIdx.x * 256 + threadIdx.x;
  const int c = blockIdx.y;
  const int b = blockIdx.z;
  float A[DS], h[DS];
  const size_t o = (((size_t)b * NC + c) * DM + d) * DS;
#pragma unroll
  for (int n = 0; n < DS; ++n) {
    A[n] = -__expf(A_log[d * DS + n]);
    h[n] = Hin[o + n];
  }
  const float Dd = Dvec[d];
  const int l0 = c * LC;
  size_t idx = ((size_t)b * LL + l0) * DM + d;
  const float* brow = &Bp[((size_t)b * LL + l0) * DS];
  const float* crow = &Cp[((size_t)b * LL + l0) * DS];
  float dtv = DT[idx], xv = X[idx];
  for (int l = 0; l < LC; ++l) {
    float ndt = 0.f, nx = 0.f;
    if (l + 1 < LC) { ndt = DT[idx + DM]; nx = X[idx + DM]; }  // prefetch
    const float dx = dtv * xv;
    float y = 0.f;
#pragma unroll
    for (int n = 0; n < DS; ++n) {
      const float dA = __expf(dtv * A[n]);
      h[n] = fmaf(dA, h[n], dx * brow[n]);
      y = fmaf(h[n], crow[n], y);
    }
    Y[idx] = fmaf(Dd, xv, y);
    brow += DS; crow += DS;
    idx += DM;
    dtv = ndt; xv = nx;
  }
}

// ---------------- launch ----------------
// Workspace layout (floats):
//   DT  : 8192*1024          = 8388608
//   BP  : 8192*16            =  131072
//   CP  : 8192*16            =  131072
//   PP  : 4*32*1024*16       = 2097152   (reused as Hin after combine)
//   HP  : 4*32*1024*16       = 2097152
// total = 12845056 floats = 51,380,224 bytes of d_ws.
extern "C" void kernel_launch(void* const* d_in, const int* in_sizes, int n_in,
                              void* d_out, int out_size, void* d_ws, size_t ws_size,
                              hipStream_t stream)
{
  const float* x     = (const float*)d_in[0];
  const float* W_dt  = (const float*)d_in[1];
  const float* b_dt  = (const float*)d_in[2];
  const float* W_B   = (const float*)d_in[3];
  const float* W_C   = (const float*)d_in[4];
  const float* A_log = (const float*)d_in[5];
  const float* Dv    = (const float*)d_in[6];
  float* Y  = (float*)d_out;
  float* ws = (float*)d_ws;

  float* DT = ws;
  float* BP = DT + (size_t)8192 * 1024;
  float* CP = BP + (size_t)8192 * DS;
  float* PP = CP + (size_t)8192 * DS;
  float* HP = PP + (size_t)BB * NC * DM * DS;

  gemm_dt_kernel<<<dim3(DM / BN, 8192 / BM), 256, 0, stream>>>(x, W_dt, b_dt, DT);
  proj_bc_kernel<<<1024, 256, 0, stream>>>(x, W_B, W_C, BP, CP);
  scan_partial_kernel<<<dim3(DM / 256, NC, BB), 256, 0, stream>>>(DT, x, BP, A_log, PP, HP);
  combine_kernel<<<(BB * DM * DS) / 256, 256, 0, stream>>>(PP, HP);
  scan_final_kernel<<<dim3(DM / 256, NC, BB), 256, 0, stream>>>(DT, x, BP, CP, A_log, Dv, PP, Y);
}

// Round 2
// 178.695 us; speedup vs baseline: 2.1748x; 2.1748x over previous
//
#include <hip/hip_runtime.h>
#include <hip/hip_bf16.h>
#include <math.h>

// Problem constants
#define DM 1024    // d_model
#define DS 16      // d_state
#define BB 4       // batch
#define LL 2048    // seq len
#define LC 32      // scan chunk length
#define NC (LL/LC) // 64 chunks
#define MT 8192    // B*L tokens

typedef __attribute__((ext_vector_type(8))) short short8;
typedef __attribute__((ext_vector_type(4))) float floatx4;

// ---------------- Kernel 0: f32 -> bf16 convert (X and W_dt) ----------------
__global__ __launch_bounds__(256) void convert_kernel(
    const float* __restrict__ X, const float* __restrict__ W,
    __hip_bfloat16* __restrict__ Xb, __hip_bfloat16* __restrict__ Wb)
{
  const size_t i = (size_t)blockIdx.x * 256 + threadIdx.x;  // unit of 8 elems
  const size_t NX = (size_t)MT * DM / 8;                    // 1048576 units
  const float* src;
  __hip_bfloat16* dst;
  size_t u;
  if (i < NX) { src = X; dst = Xb; u = i; }
  else        { src = W; dst = Wb; u = i - NX; }
  const float4 a = *(const float4*)&src[u * 8];
  const float4 b = *(const float4*)&src[u * 8 + 4];
  union { short8 v; __hip_bfloat16 h[8]; } o;
  o.h[0] = __float2bfloat16(a.x); o.h[1] = __float2bfloat16(a.y);
  o.h[2] = __float2bfloat16(a.z); o.h[3] = __float2bfloat16(a.w);
  o.h[4] = __float2bfloat16(b.x); o.h[5] = __float2bfloat16(b.y);
  o.h[6] = __float2bfloat16(b.z); o.h[7] = __float2bfloat16(b.w);
  *(short8*)&dst[u * 8] = o.v;
}

// ---------------- Kernel 1: dt = softplus(Xb @ Wb^T + b_dt), bf16 MFMA ------
// m97 structure: 128x128 tile, BK=32, 4 waves (2x2), 4x4 16x16x32 frags/wave,
// global_load_lds width 16, single-buffered LDS.
__global__ __launch_bounds__(256) void gemm_dt_mfma(
    const __hip_bfloat16* __restrict__ Xb, const __hip_bfloat16* __restrict__ Wb,
    const float* __restrict__ bias, float* __restrict__ DT)
{
  __shared__ short As[128 * 32];
  __shared__ short Bs[128 * 32];
  const int tid  = threadIdx.x;
  const int lane = tid & 63;
  const int wid  = tid >> 6;        // 0..3
  const int wm   = wid >> 1, wn = wid & 1;
  const int row0 = blockIdx.y * 128;
  const int col0 = blockIdx.x * 128;

  const floatx4 zero = {0.f, 0.f, 0.f, 0.f};
  floatx4 acc[4][4];
#pragma unroll
  for (int i = 0; i < 4; ++i)
#pragma unroll
    for (int j = 0; j < 4; ++j) acc[i][j] = zero;

  for (int k0 = 0; k0 < DM; k0 += 32) {
#pragma unroll
    for (int q = 0; q < 2; ++q) {
      const int fe = q * 256 + tid;    // 8-elem group id, 0..511
      const int r  = fe >> 2;          // tile row 0..127
      const int kk = (fe & 3) * 8;     // k offset 0,8,16,24
      __builtin_amdgcn_global_load_lds(
          (const __attribute__((address_space(1))) void*)&Xb[(size_t)(row0 + r) * DM + k0 + kk],
          (__attribute__((address_space(3))) void*)&As[fe * 8], 16, 0, 0);
      __builtin_amdgcn_global_load_lds(
          (const __attribute__((address_space(1))) void*)&Wb[(size_t)(col0 + r) * DM + k0 + kk],
          (__attribute__((address_space(3))) void*)&Bs[fe * 8], 16, 0, 0);
    }
    __syncthreads();

    short8 af[4], bfr[4];
#pragma unroll
    for (int i = 0; i < 4; ++i) {
      const int ar = wm * 64 + i * 16 + (lane & 15);
      af[i]  = *(const short8*)&As[ar * 32 + (lane >> 4) * 8];
      const int br = wn * 64 + i * 16 + (lane & 15);
      bfr[i] = *(const short8*)&Bs[br * 32 + (lane >> 4) * 8];
    }
#pragma unroll
    for (int i = 0; i < 4; ++i)
#pragma unroll
      for (int j = 0; j < 4; ++j)
        acc[i][j] = __builtin_amdgcn_mfma_f32_16x16x32_bf16(af[i], bfr[j], acc[i][j], 0, 0, 0);
    __syncthreads();
  }

  // epilogue: bias + softplus, C/D layout col=lane&15, row=(lane>>4)*4+r
  const int cl = lane & 15;
  const int rg = lane >> 4;
#pragma unroll
  for (int i = 0; i < 4; ++i) {
#pragma unroll
    for (int r = 0; r < 4; ++r) {
      const size_t row = (size_t)(row0 + wm * 64 + i * 16 + rg * 4 + r);
#pragma unroll
      for (int j = 0; j < 4; ++j) {
        const int col = col0 + wn * 64 + j * 16 + cl;
        const float v = acc[i][j][r] + bias[col];
        DT[row * DM + col] = fmaxf(v, 0.f) + log1pf(__expf(-fabsf(v)));
      }
    }
  }
}

// ---------------- Kernel 2: Bp/Cp = X @ {W_B,W_C}^T  (skinny, f32) ----------
__global__ __launch_bounds__(256) void proj_bc_kernel(
    const float* __restrict__ X, const float* __restrict__ WB,
    const float* __restrict__ WC, float* __restrict__ Bp, float* __restrict__ Cp)
{
  const int lane = threadIdx.x & 63;
  const int wid  = (blockIdx.x * 256 + threadIdx.x) >> 6;  // 0..4095
  const size_t r0 = (size_t)wid * 2;
  float aB0[DS] = {}, aB1[DS] = {}, aC0[DS] = {}, aC1[DS] = {};

  for (int k = lane; k < DM; k += 64) {
    const float x0 = X[r0 * DM + k];
    const float x1 = X[(r0 + 1) * DM + k];
#pragma unroll
    for (int n = 0; n < DS; ++n) {
      const float wb = WB[n * DM + k];
      const float wc = WC[n * DM + k];
      aB0[n] = fmaf(x0, wb, aB0[n]);
      aB1[n] = fmaf(x1, wb, aB1[n]);
      aC0[n] = fmaf(x0, wc, aC0[n]);
      aC1[n] = fmaf(x1, wc, aC1[n]);
    }
  }
#pragma unroll
  for (int n = 0; n < DS; ++n) {
#pragma unroll
    for (int off = 32; off > 0; off >>= 1) {
      aB0[n] += __shfl_xor(aB0[n], off, 64);
      aB1[n] += __shfl_xor(aB1[n], off, 64);
      aC0[n] += __shfl_xor(aC0[n], off, 64);
      aC1[n] += __shfl_xor(aC1[n], off, 64);
    }
  }
  if (lane == 0) {
#pragma unroll
    for (int n = 0; n < DS; ++n) {
      Bp[r0 * DS + n]       = aB0[n];
      Bp[(r0 + 1) * DS + n] = aB1[n];
      Cp[r0 * DS + n]       = aC0[n];
      Cp[(r0 + 1) * DS + n] = aC1[n];
    }
  }
}

// ---------------- Kernel 3: per-chunk local scan (pass A) ----------------
__global__ __launch_bounds__(256) void scan_partial_kernel(
    const float* __restrict__ DT, const float* __restrict__ X,
    const float* __restrict__ Bp, const float* __restrict__ A_log,
    float* __restrict__ PP, float* __restrict__ HP)
{
  const int d = blockIdx.x * 256 + threadIdx.x;
  const int c = blockIdx.y;
  const int b = blockIdx.z;
  float A[DS], h[DS], P[DS];
  const float4* arow = (const float4*)&A_log[(size_t)d * DS];
#pragma unroll
  for (int m = 0; m < 4; ++m) {
    const float4 a4 = arow[m];
    A[m*4+0] = -__expf(a4.x); A[m*4+1] = -__expf(a4.y);
    A[m*4+2] = -__expf(a4.z); A[m*4+3] = -__expf(a4.w);
  }
#pragma unroll
  for (int n = 0; n < DS; ++n) { h[n] = 0.f; P[n] = 1.f; }

  const int l0 = c * LC;
  size_t idx = ((size_t)b * LL + l0) * DM + d;
  const float4* bv = (const float4*)&Bp[((size_t)b * LL + l0) * DS];

  float dtb[4], xb[4];
#pragma unroll
  for (int u = 0; u < 4; ++u) { dtb[u] = DT[idx + (size_t)u * DM]; xb[u] = X[idx + (size_t)u * DM]; }

  for (int l = 0; l < LC; l += 4) {
    float dtn[4], xn[4];
    if (l + 4 < LC) {
#pragma unroll
      for (int u = 0; u < 4; ++u) {
        dtn[u] = DT[idx + (size_t)(u + 4) * DM];
        xn[u]  = X[idx + (size_t)(u + 4) * DM];
      }
    }
#pragma unroll
    for (int u = 0; u < 4; ++u) {
      const float dtv = dtb[u], xv = xb[u];
      const float dx = dtv * xv;
      const float4 b0 = bv[(l+u)*4+0], b1 = bv[(l+u)*4+1];
      const float4 b2 = bv[(l+u)*4+2], b3 = bv[(l+u)*4+3];
      const float bb[DS] = {b0.x,b0.y,b0.z,b0.w, b1.x,b1.y,b1.z,b1.w,
                            b2.x,b2.y,b2.z,b2.w, b3.x,b3.y,b3.z,b3.w};
#pragma unroll
      for (int n = 0; n < DS; ++n) {
        const float dA = __expf(dtv * A[n]);
        P[n] *= dA;
        h[n] = fmaf(dA, h[n], dx * bb[n]);
      }
    }
    idx += (size_t)4 * DM;
#pragma unroll
    for (int u = 0; u < 4; ++u) { dtb[u] = dtn[u]; xb[u] = xn[u]; }
  }
  const size_t o = (((size_t)b * NC + c) * DM + d) * DS;
  float4* pp = (float4*)&PP[o];
  float4* hp = (float4*)&HP[o];
#pragma unroll
  for (int m = 0; m < 4; ++m) {
    pp[m] = make_float4(P[m*4+0], P[m*4+1], P[m*4+2], P[m*4+3]);
    hp[m] = make_float4(h[m*4+0], h[m*4+1], h[m*4+2], h[m*4+3]);
  }
}

// ---------------- Kernel 4: combine chunk prefixes (sequential over NC) -----
__global__ __launch_bounds__(256) void combine_kernel(
    float* __restrict__ PP, const float* __restrict__ HP)
{
  const int idx = blockIdx.x * 256 + threadIdx.x;  // over B*DM*DS = 65536
  const int b  = idx >> 14;
  const int dn = idx & 16383;
  float h = 0.f;
#pragma unroll 4
  for (int c = 0; c < NC; ++c) {
    const size_t o = (((size_t)b * NC + c) << 14) + dn;
    const float p  = PP[o];
    const float hp = HP[o];
    PP[o] = h;              // Hin for chunk c
    h = fmaf(p, h, hp);
  }
}

// ---------------- Kernel 5: final scan + output (pass B) ----------------
__global__ __launch_bounds__(256) void scan_final_kernel(
    const float* __restrict__ DT, const float* __restrict__ X,
    const float* __restrict__ Bp, const float* __restrict__ Cp,
    const float* __restrict__ A_log, const float* __restrict__ Dvec,
    const float* __restrict__ Hin, float* __restrict__ Y)
{
  const int d = blockIdx.x * 256 + threadIdx.x;
  const int c = blockIdx.y;
  const int b = blockIdx.z;
  float A[DS], h[DS];
  const float4* arow = (const float4*)&A_log[(size_t)d * DS];
  const size_t o = (((size_t)b * NC + c) * DM + d) * DS;
  const float4* hin = (const float4*)&Hin[o];
#pragma unroll
  for (int m = 0; m < 4; ++m) {
    const float4 a4 = arow[m];
    A[m*4+0] = -__expf(a4.x); A[m*4+1] = -__expf(a4.y);
    A[m*4+2] = -__expf(a4.z); A[m*4+3] = -__expf(a4.w);
    const float4 h4 = hin[m];
    h[m*4+0] = h4.x; h[m*4+1] = h4.y; h[m*4+2] = h4.z; h[m*4+3] = h4.w;
  }
  const float Dd = Dvec[d];
  const int l0 = c * LC;
  size_t idx = ((size_t)b * LL + l0) * DM + d;
  const float4* bv = (const float4*)&Bp[((size_t)b * LL + l0) * DS];
  const float4* cv = (const float4*)&Cp[((size_t)b * LL + l0) * DS];

  float dtb[4], xb[4];
#pragma unroll
  for (int u = 0; u < 4; ++u) { dtb[u] = DT[idx + (size_t)u * DM]; xb[u] = X[idx + (size_t)u * DM]; }

  for (int l = 0; l < LC; l += 4) {
    float dtn[4], xn[4];
    if (l + 4 < LC) {
#pragma unroll
      for (int u = 0; u < 4; ++u) {
        dtn[u] = DT[idx + (size_t)(u + 4) * DM];
        xn[u]  = X[idx + (size_t)(u + 4) * DM];
      }
    }
#pragma unroll
    for (int u = 0; u < 4; ++u) {
      const float dtv = dtb[u], xv = xb[u];
      const float dx = dtv * xv;
      const float4 b0 = bv[(l+u)*4+0], b1 = bv[(l+u)*4+1];
      const float4 b2 = bv[(l+u)*4+2], b3 = bv[(l+u)*4+3];
      const float bb[DS] = {b0.x,b0.y,b0.z,b0.w, b1.x,b1.y,b1.z,b1.w,
                            b2.x,b2.y,b2.z,b2.w, b3.x,b3.y,b3.z,b3.w};
      const float4 c0 = cv[(l+u)*4+0], c1 = cv[(l+u)*4+1];
      const float4 c2 = cv[(l+u)*4+2], c3 = cv[(l+u)*4+3];
      const float cc[DS] = {c0.x,c0.y,c0.z,c0.w, c1.x,c1.y,c1.z,c1.w,
                            c2.x,c2.y,c2.z,c2.w, c3.x,c3.y,c3.z,c3.w};
      float y = 0.f;
#pragma unroll
      for (int n = 0; n < DS; ++n) {
        const float dA = __expf(dtv * A[n]);
        h[n] = fmaf(dA, h[n], dx * bb[n]);
        y = fmaf(h[n], cc[n], y);
      }
      Y[idx + (size_t)u * DM] = fmaf(Dd, xv, y);
    }
    idx += (size_t)4 * DM;
#pragma unroll
    for (int u = 0; u < 4; ++u) { dtb[u] = dtn[u]; xb[u] = xn[u]; }
  }
}

// ---------------- launch ----------------
// Workspace layout (float slots):
//   DT  : 8192*1024           = 8388608
//   BP  : 8192*16             =  131072
//   CP  : 8192*16             =  131072
//   R   : union {
//           phase1: Xbf (8388608 bf16 = 4194304 slots) + Wbf (1048576 bf16 = 524288 slots)
//           phase2: PP (4194304) + HP (4194304)
//         }                   = 8388608
// total = 17039360 floats = 68,157,440 bytes of d_ws.
extern "C" void kernel_launch(void* const* d_in, const int* in_sizes, int n_in,
                              void* d_out, int out_size, void* d_ws, size_t ws_size,
                              hipStream_t stream)
{
  const float* x     = (const float*)d_in[0];
  const float* W_dt  = (const float*)d_in[1];
  const float* b_dt  = (const float*)d_in[2];
  const float* W_B   = (const float*)d_in[3];
  const float* W_C   = (const float*)d_in[4];
  const float* A_log = (const float*)d_in[5];
  const float* Dv    = (const float*)d_in[6];
  float* Y  = (float*)d_out;
  float* ws = (float*)d_ws;

  float* DT = ws;
  float* BP = DT + (size_t)MT * DM;
  float* CP = BP + (size_t)MT * DS;
  float* R  = CP + (size_t)MT * DS;
  __hip_bfloat16* Xb = (__hip_bfloat16*)R;
  __hip_bfloat16* Wb = (__hip_bfloat16*)(R + (size_t)MT * DM / 2);
  float* PP = R;
  float* HP = R + (size_t)BB * NC * DM * DS;

  convert_kernel<<<(MT * DM / 8 + DM * DM / 8) / 256, 256, 0, stream>>>(x, W_dt, Xb, Wb);
  gemm_dt_mfma<<<dim3(DM / 128, MT / 128), 256, 0, stream>>>(Xb, Wb, b_dt, DT);
  proj_bc_kernel<<<1024, 256, 0, stream>>>(x, W_B, W_C, BP, CP);
  scan_partial_kernel<<<dim3(DM / 256, NC, BB), 256, 0, stream>>>(DT, x, BP, A_log, PP, HP);
  combine_kernel<<<(BB * DM * DS) / 256, 256, 0, stream>>>(PP, HP);
  scan_final_kernel<<<dim3(DM / 256, NC, BB), 256, 0, stream>>>(DT, x, BP, CP, A_log, Dv, PP, Y);
}

// Round 3
// 178.582 us; speedup vs baseline: 2.1762x; 1.0006x over previous
//
#include <hip/hip_runtime.h>
#include <hip/hip_bf16.h>
#include <math.h>

// Problem constants
#define DM 1024    // d_model
#define DS 16      // d_state
#define BB 4       // batch
#define LL 2048    // seq len
#define LC 32      // scan chunk length
#define NC (LL/LC) // 64 chunks
#define MT 8192    // B*L tokens
#define NT 32      // GEMM k-steps (DM/32)

typedef __attribute__((ext_vector_type(8))) short short8;
typedef __attribute__((ext_vector_type(4))) float floatx4;

// ---- Kernel 1: prep = {proj Bp/Cp + X->bf16} (blocks 0..1023) U {W_dt->bf16} ----
__global__ __launch_bounds__(256) void prep_kernel(
    const float* __restrict__ X, const float* __restrict__ W_dt,
    const float* __restrict__ WB, const float* __restrict__ WC,
    float* __restrict__ Bp, float* __restrict__ Cp,
    __hip_bfloat16* __restrict__ Xb, __hip_bfloat16* __restrict__ Wb)
{
  if (blockIdx.x >= 1024) {
    // convert W_dt (1024x1024 f32 -> bf16), 8 elems/thread
    const size_t u = ((size_t)(blockIdx.x - 1024) * 256 + threadIdx.x);
    const float4 a = *(const float4*)&W_dt[u * 8];
    const float4 b = *(const float4*)&W_dt[u * 8 + 4];
    union { short8 v; __hip_bfloat16 h[8]; } o;
    o.h[0] = __float2bfloat16(a.x); o.h[1] = __float2bfloat16(a.y);
    o.h[2] = __float2bfloat16(a.z); o.h[3] = __float2bfloat16(a.w);
    o.h[4] = __float2bfloat16(b.x); o.h[5] = __float2bfloat16(b.y);
    o.h[6] = __float2bfloat16(b.z); o.h[7] = __float2bfloat16(b.w);
    *(short8*)&Wb[u * 8] = o.v;
    return;
  }
  // proj: wave per 2 token rows; also emit bf16 X
  const int lane = threadIdx.x & 63;
  const int wid  = (blockIdx.x * 256 + threadIdx.x) >> 6;  // 0..4095
  const size_t r0 = (size_t)wid * 2;
  float aB0[DS] = {}, aB1[DS] = {}, aC0[DS] = {}, aC1[DS] = {};

  for (int k = lane; k < DM; k += 64) {
    const float x0 = X[r0 * DM + k];
    const float x1 = X[(r0 + 1) * DM + k];
    Xb[r0 * DM + k]       = __float2bfloat16(x0);
    Xb[(r0 + 1) * DM + k] = __float2bfloat16(x1);
#pragma unroll
    for (int n = 0; n < DS; ++n) {
      const float wb = WB[n * DM + k];
      const float wc = WC[n * DM + k];
      aB0[n] = fmaf(x0, wb, aB0[n]);
      aB1[n] = fmaf(x1, wb, aB1[n]);
      aC0[n] = fmaf(x0, wc, aC0[n]);
      aC1[n] = fmaf(x1, wc, aC1[n]);
    }
  }
#pragma unroll
  for (int n = 0; n < DS; ++n) {
#pragma unroll
    for (int off = 32; off > 0; off >>= 1) {
      aB0[n] += __shfl_xor(aB0[n], off, 64);
      aB1[n] += __shfl_xor(aB1[n], off, 64);
      aC0[n] += __shfl_xor(aC0[n], off, 64);
      aC1[n] += __shfl_xor(aC1[n], off, 64);
    }
  }
  if (lane == 0) {
#pragma unroll
    for (int n = 0; n < DS; ++n) {
      Bp[r0 * DS + n]       = aB0[n];
      Bp[(r0 + 1) * DS + n] = aB1[n];
      Cp[r0 * DS + n]       = aC0[n];
      Cp[(r0 + 1) * DS + n] = aC1[n];
    }
  }
}

// ---- Kernel 2: dt = softplus(Xb @ Wb^T + b_dt) -> bf16, MFMA, 2-deep pipeline ----
// 128x128 tile, BK=32, 4 waves (2x2), 4x4 16x16x32 frags/wave.
// 3 LDS buffers; STAGE(t+2) in flight while computing t; vmcnt(4) mid-loop.
__global__ __launch_bounds__(256) void gemm_dt_mfma(
    const __hip_bfloat16* __restrict__ Xb, const __hip_bfloat16* __restrict__ Wb,
    const float* __restrict__ bias, __hip_bfloat16* __restrict__ DTb)
{
  __shared__ short As[3][128 * 32];
  __shared__ short Bs[3][128 * 32];
  const int tid  = threadIdx.x;
  const int lane = tid & 63;
  const int wid  = tid >> 6;        // 0..3
  const int wm   = wid >> 1, wn = wid & 1;
  const int row0 = blockIdx.y * 128;
  const int col0 = blockIdx.x * 128;

  const floatx4 zero = {0.f, 0.f, 0.f, 0.f};
  floatx4 acc[4][4];
#pragma unroll
  for (int i = 0; i < 4; ++i)
#pragma unroll
    for (int j = 0; j < 4; ++j) acc[i][j] = zero;

  // STAGE: 4 global_load_lds per thread (2 for As, 2 for Bs), 16B each
  auto STAGE = [&](int buf, int t) {
    const int k0 = t * 32;
#pragma unroll
    for (int q = 0; q < 2; ++q) {
      const int fe = q * 256 + tid;    // 8-elem group id, 0..511
      const int r  = fe >> 2;          // tile row 0..127
      const int kk = (fe & 3) * 8;     // k offset 0,8,16,24
      __builtin_amdgcn_global_load_lds(
          (const __attribute__((address_space(1))) void*)&Xb[(size_t)(row0 + r) * DM + k0 + kk],
          (__attribute__((address_space(3))) void*)&As[buf][fe * 8], 16, 0, 0);
      __builtin_amdgcn_global_load_lds(
          (const __attribute__((address_space(1))) void*)&Wb[(size_t)(col0 + r) * DM + k0 + kk],
          (__attribute__((address_space(3))) void*)&Bs[buf][fe * 8], 16, 0, 0);
    }
  };

  STAGE(0, 0);
  STAGE(1, 1);
  int cur = 0;
  for (int t = 0; t < NT; ++t) {
    // wait until this tile's 4 loads landed (t+1's 4 may stay in flight)
    if (t < NT - 1) asm volatile("s_waitcnt vmcnt(4)" ::: "memory");
    else            asm volatile("s_waitcnt vmcnt(0)" ::: "memory");
    __builtin_amdgcn_s_barrier();
    __builtin_amdgcn_sched_barrier(0);

    int c2 = cur + 2; if (c2 >= 3) c2 -= 3;
    if (t + 2 < NT) STAGE(c2, t + 2);   // prefetch 2 tiles ahead

    short8 af[4], bfr[4];
#pragma unroll
    for (int i = 0; i < 4; ++i) {
      const int ar = wm * 64 + i * 16 + (lane & 15);
      af[i]  = *(const short8*)&As[cur][ar * 32 + (lane >> 4) * 8];
      const int br = wn * 64 + i * 16 + (lane & 15);
      bfr[i] = *(const short8*)&Bs[cur][br * 32 + (lane >> 4) * 8];
    }
#pragma unroll
    for (int i = 0; i < 4; ++i)
#pragma unroll
      for (int j = 0; j < 4; ++j)
        acc[i][j] = __builtin_amdgcn_mfma_f32_16x16x32_bf16(af[i], bfr[j], acc[i][j], 0, 0, 0);

    cur += 1; if (cur >= 3) cur -= 3;
  }

  // epilogue: bias + softplus -> bf16. C/D layout: col=lane&15, row=(lane>>4)*4+r
  const int cl = lane & 15;
  const int rg = lane >> 4;
#pragma unroll
  for (int i = 0; i < 4; ++i) {
#pragma unroll
    for (int r = 0; r < 4; ++r) {
      const size_t row = (size_t)(row0 + wm * 64 + i * 16 + rg * 4 + r);
#pragma unroll
      for (int j = 0; j < 4; ++j) {
        const int col = col0 + wn * 64 + j * 16 + cl;
        const float v = acc[i][j][r] + bias[col];
        DTb[row * DM + col] =
            __float2bfloat16(fmaxf(v, 0.f) + log1pf(__expf(-fabsf(v))));
      }
    }
  }
}

// ---- Kernel 3: per-chunk local scan (pass A), bf16 dt/x inputs ----
__global__ __launch_bounds__(256) void scan_partial_kernel(
    const __hip_bfloat16* __restrict__ DT, const __hip_bfloat16* __restrict__ X,
    const float* __restrict__ Bp, const float* __restrict__ A_log,
    float* __restrict__ PP, float* __restrict__ HP)
{
  const int d = blockIdx.x * 256 + threadIdx.x;
  const int c = blockIdx.y;
  const int b = blockIdx.z;
  float A[DS], h[DS], P[DS];
  const float4* arow = (const float4*)&A_log[(size_t)d * DS];
#pragma unroll
  for (int m = 0; m < 4; ++m) {
    const float4 a4 = arow[m];
    A[m*4+0] = -__expf(a4.x); A[m*4+1] = -__expf(a4.y);
    A[m*4+2] = -__expf(a4.z); A[m*4+3] = -__expf(a4.w);
  }
#pragma unroll
  for (int n = 0; n < DS; ++n) { h[n] = 0.f; P[n] = 1.f; }

  const int l0 = c * LC;
  size_t idx = ((size_t)b * LL + l0) * DM + d;
  const float4* bv = (const float4*)&Bp[((size_t)b * LL + l0) * DS];

  float dtb[4], xb[4];
#pragma unroll
  for (int u = 0; u < 4; ++u) {
    dtb[u] = __bfloat162float(DT[idx + (size_t)u * DM]);
    xb[u]  = __bfloat162float(X[idx + (size_t)u * DM]);
  }

  for (int l = 0; l < LC; l += 4) {
    float dtn[4], xn[4];
    if (l + 4 < LC) {
#pragma unroll
      for (int u = 0; u < 4; ++u) {
        dtn[u] = __bfloat162float(DT[idx + (size_t)(u + 4) * DM]);
        xn[u]  = __bfloat162float(X[idx + (size_t)(u + 4) * DM]);
      }
    }
#pragma unroll
    for (int u = 0; u < 4; ++u) {
      const float dtv = dtb[u], xv = xb[u];
      const float dx = dtv * xv;
      const float4 b0 = bv[(l+u)*4+0], b1 = bv[(l+u)*4+1];
      const float4 b2 = bv[(l+u)*4+2], b3 = bv[(l+u)*4+3];
      const float bb[DS] = {b0.x,b0.y,b0.z,b0.w, b1.x,b1.y,b1.z,b1.w,
                            b2.x,b2.y,b2.z,b2.w, b3.x,b3.y,b3.z,b3.w};
#pragma unroll
      for (int n = 0; n < DS; ++n) {
        const float dA = __expf(dtv * A[n]);
        P[n] *= dA;
        h[n] = fmaf(dA, h[n], dx * bb[n]);
      }
    }
    idx += (size_t)4 * DM;
#pragma unroll
    for (int u = 0; u < 4; ++u) { dtb[u] = dtn[u]; xb[u] = xn[u]; }
  }
  const size_t o = (((size_t)b * NC + c) * DM + d) * DS;
  float4* pp = (float4*)&PP[o];
  float4* hp = (float4*)&HP[o];
#pragma unroll
  for (int m = 0; m < 4; ++m) {
    pp[m] = make_float4(P[m*4+0], P[m*4+1], P[m*4+2], P[m*4+3]);
    hp[m] = make_float4(h[m*4+0], h[m*4+1], h[m*4+2], h[m*4+3]);
  }
}

// ---- Kernel 4: combine chunk prefixes (sequential over NC) ----
__global__ __launch_bounds__(256) void combine_kernel(
    float* __restrict__ PP, const float* __restrict__ HP)
{
  const int idx = blockIdx.x * 256 + threadIdx.x;  // over B*DM*DS = 65536
  const int b  = idx >> 14;
  const int dn = idx & 16383;
  float h = 0.f;
#pragma unroll 4
  for (int c = 0; c < NC; ++c) {
    const size_t o = (((size_t)b * NC + c) << 14) + dn;
    const float p  = PP[o];
    const float hp = HP[o];
    PP[o] = h;              // Hin for chunk c
    h = fmaf(p, h, hp);
  }
}

// ---- Kernel 5: final scan + output (pass B), bf16 dt/x inputs ----
__global__ __launch_bounds__(256) void scan_final_kernel(
    const __hip_bfloat16* __restrict__ DT, const __hip_bfloat16* __restrict__ X,
    const float* __restrict__ Bp, const float* __restrict__ Cp,
    const float* __restrict__ A_log, const float* __restrict__ Dvec,
    const float* __restrict__ Hin, float* __restrict__ Y)
{
  const int d = blockIdx.x * 256 + threadIdx.x;
  const int c = blockIdx.y;
  const int b = blockIdx.z;
  float A[DS], h[DS];
  const float4* arow = (const float4*)&A_log[(size_t)d * DS];
  const size_t o = (((size_t)b * NC + c) * DM + d) * DS;
  const float4* hin = (const float4*)&Hin[o];
#pragma unroll
  for (int m = 0; m < 4; ++m) {
    const float4 a4 = arow[m];
    A[m*4+0] = -__expf(a4.x); A[m*4+1] = -__expf(a4.y);
    A[m*4+2] = -__expf(a4.z); A[m*4+3] = -__expf(a4.w);
    const float4 h4 = hin[m];
    h[m*4+0] = h4.x; h[m*4+1] = h4.y; h[m*4+2] = h4.z; h[m*4+3] = h4.w;
  }
  const float Dd = Dvec[d];
  const int l0 = c * LC;
  size_t idx = ((size_t)b * LL + l0) * DM + d;
  const float4* bv = (const float4*)&Bp[((size_t)b * LL + l0) * DS];
  const float4* cv = (const float4*)&Cp[((size_t)b * LL + l0) * DS];

  float dtb[4], xb[4];
#pragma unroll
  for (int u = 0; u < 4; ++u) {
    dtb[u] = __bfloat162float(DT[idx + (size_t)u * DM]);
    xb[u]  = __bfloat162float(X[idx + (size_t)u * DM]);
  }

  for (int l = 0; l < LC; l += 4) {
    float dtn[4], xn[4];
    if (l + 4 < LC) {
#pragma unroll
      for (int u = 0; u < 4; ++u) {
        dtn[u] = __bfloat162float(DT[idx + (size_t)(u + 4) * DM]);
        xn[u]  = __bfloat162float(X[idx + (size_t)(u + 4) * DM]);
      }
    }
#pragma unroll
    for (int u = 0; u < 4; ++u) {
      const float dtv = dtb[u], xv = xb[u];
      const float dx = dtv * xv;
      const float4 b0 = bv[(l+u)*4+0], b1 = bv[(l+u)*4+1];
      const float4 b2 = bv[(l+u)*4+2], b3 = bv[(l+u)*4+3];
      const float bb[DS] = {b0.x,b0.y,b0.z,b0.w, b1.x,b1.y,b1.z,b1.w,
                            b2.x,b2.y,b2.z,b2.w, b3.x,b3.y,b3.z,b3.w};
      const float4 c0 = cv[(l+u)*4+0], c1 = cv[(l+u)*4+1];
      const float4 c2 = cv[(l+u)*4+2], c3 = cv[(l+u)*4+3];
      const float cc[DS] = {c0.x,c0.y,c0.z,c0.w, c1.x,c1.y,c1.z,c1.w,
                            c2.x,c2.y,c2.z,c2.w, c3.x,c3.y,c3.z,c3.w};
      float y = 0.f;
#pragma unroll
      for (int n = 0; n < DS; ++n) {
        const float dA = __expf(dtv * A[n]);
        h[n] = fmaf(dA, h[n], dx * bb[n]);
        y = fmaf(h[n], cc[n], y);
      }
      Y[idx + (size_t)u * DM] = fmaf(Dd, xv, y);
    }
    idx += (size_t)4 * DM;
#pragma unroll
    for (int u = 0; u < 4; ++u) { dtb[u] = dtn[u]; xb[u] = xn[u]; }
  }
}

// ---- launch ----
// Workspace (float slots):
//   DTb : MT*DM bf16            = 4194304 slots
//   BP  : MT*DS                 =  131072
//   CP  : MT*DS                 =  131072
//   Xb  : MT*DM bf16            = 4194304 slots
//   U   : union { Wb (DM*DM bf16 = 524288 slots, dead after GEMM),
//                 PP (BB*NC*DM*DS = 4194304, live after GEMM) } = 4194304
//   HP  : BB*NC*DM*DS           = 4194304
// total = 16976128 floats = 67,904,512 bytes.
extern "C" void kernel_launch(void* const* d_in, const int* in_sizes, int n_in,
                              void* d_out, int out_size, void* d_ws, size_t ws_size,
                              hipStream_t stream)
{
  const float* x     = (const float*)d_in[0];
  const float* W_dt  = (const float*)d_in[1];
  const float* b_dt  = (const float*)d_in[2];
  const float* W_B   = (const float*)d_in[3];
  const float* W_C   = (const float*)d_in[4];
  const float* A_log = (const float*)d_in[5];
  const float* Dv    = (const float*)d_in[6];
  float* Y  = (float*)d_out;
  float* ws = (float*)d_ws;

  __hip_bfloat16* DTb = (__hip_bfloat16*)ws;
  float* BP = ws + (size_t)MT * DM / 2;
  float* CP = BP + (size_t)MT * DS;
  __hip_bfloat16* Xb = (__hip_bfloat16*)(CP + (size_t)MT * DS);
  float* U  = CP + (size_t)MT * DS + (size_t)MT * DM / 2;
  __hip_bfloat16* Wb = (__hip_bfloat16*)U;
  float* PP = U;
  float* HP = U + (size_t)BB * NC * DM * DS;

  prep_kernel<<<1536, 256, 0, stream>>>(x, W_dt, W_B, W_C, BP, CP, Xb, Wb);
  gemm_dt_mfma<<<dim3(DM / 128, MT / 128), 256, 0, stream>>>(Xb, Wb, b_dt, DTb);
  scan_partial_kernel<<<dim3(DM / 256, NC, BB), 256, 0, stream>>>(DTb, Xb, BP, A_log, PP, HP);
  combine_kernel<<<(BB * DM * DS) / 256, 256, 0, stream>>>(PP, HP);
  scan_final_kernel<<<dim3(DM / 256, NC, BB), 256, 0, stream>>>(DTb, Xb, BP, CP, A_log, Dv, PP, Y);
}

// Round 4
// 159.311 us; speedup vs baseline: 2.4395x; 1.1210x over previous
//
#include <hip/hip_runtime.h>
#include <hip/hip_bf16.h>
#include <math.h>

// Problem constants
#define DM 1024    // d_model
#define DS 16      // d_state
#define BB 4       // batch
#define LL 2048    // seq len
#define LC 32      // scan chunk length
#define NC (LL/LC) // 64 chunks
#define MT 8192    // B*L tokens
#define NT 32      // GEMM k-steps (DM/32)

typedef __attribute__((ext_vector_type(8))) short short8;
typedef __attribute__((ext_vector_type(4))) float floatx4;

__device__ __forceinline__ float softplus_fast(float v) {
  // max(v,0) + log(1+exp(-|v|)); abs err ~1e-6, negligible vs bf16 storage
  return fmaxf(v, 0.f) + __logf(1.f + __expf(-fabsf(v)));
}

// ---- Kernel 1: prep = {proj Bp/Cp + X->bf16} (blocks 0..1023) U {W_dt->bf16} ----
__global__ __launch_bounds__(256) void prep_kernel(
    const float* __restrict__ X, const float* __restrict__ W_dt,
    const float* __restrict__ WB, const float* __restrict__ WC,
    float* __restrict__ Bp, float* __restrict__ Cp,
    __hip_bfloat16* __restrict__ Xb, __hip_bfloat16* __restrict__ Wb)
{
  if (blockIdx.x >= 1024) {
    const size_t u = ((size_t)(blockIdx.x - 1024) * 256 + threadIdx.x);
    const float4 a = *(const float4*)&W_dt[u * 8];
    const float4 b = *(const float4*)&W_dt[u * 8 + 4];
    union { short8 v; __hip_bfloat16 h[8]; } o;
    o.h[0] = __float2bfloat16(a.x); o.h[1] = __float2bfloat16(a.y);
    o.h[2] = __float2bfloat16(a.z); o.h[3] = __float2bfloat16(a.w);
    o.h[4] = __float2bfloat16(b.x); o.h[5] = __float2bfloat16(b.y);
    o.h[6] = __float2bfloat16(b.z); o.h[7] = __float2bfloat16(b.w);
    *(short8*)&Wb[u * 8] = o.v;
    return;
  }
  const int lane = threadIdx.x & 63;
  const int wid  = (blockIdx.x * 256 + threadIdx.x) >> 6;  // 0..4095
  const size_t r0 = (size_t)wid * 2;
  float aB0[DS] = {}, aB1[DS] = {}, aC0[DS] = {}, aC1[DS] = {};

  for (int k = lane; k < DM; k += 64) {
    const float x0 = X[r0 * DM + k];
    const float x1 = X[(r0 + 1) * DM + k];
    Xb[r0 * DM + k]       = __float2bfloat16(x0);
    Xb[(r0 + 1) * DM + k] = __float2bfloat16(x1);
#pragma unroll
    for (int n = 0; n < DS; ++n) {
      const float wb = WB[n * DM + k];
      const float wc = WC[n * DM + k];
      aB0[n] = fmaf(x0, wb, aB0[n]);
      aB1[n] = fmaf(x1, wb, aB1[n]);
      aC0[n] = fmaf(x0, wc, aC0[n]);
      aC1[n] = fmaf(x1, wc, aC1[n]);
    }
  }
#pragma unroll
  for (int n = 0; n < DS; ++n) {
#pragma unroll
    for (int off = 32; off > 0; off >>= 1) {
      aB0[n] += __shfl_xor(aB0[n], off, 64);
      aB1[n] += __shfl_xor(aB1[n], off, 64);
      aC0[n] += __shfl_xor(aC0[n], off, 64);
      aC1[n] += __shfl_xor(aC1[n], off, 64);
    }
  }
  if (lane == 0) {
#pragma unroll
    for (int n = 0; n < DS; ++n) {
      Bp[r0 * DS + n]       = aB0[n];
      Bp[(r0 + 1) * DS + n] = aB1[n];
      Cp[r0 * DS + n]       = aC0[n];
      Cp[(r0 + 1) * DS + n] = aC1[n];
    }
  }
}

// ---- Kernel 2: dt = softplus(Xb @ Wb^T + b_dt) -> bf16, MFMA ----
// BM=128, BN=64, BK=32; 1024 blocks (4/CU), 4 waves (2x2), 4x2 frags/wave.
// 3 LDS buffers, 2-deep prefetch, counted vmcnt(3). XCD-swizzled tiles.
__global__ __launch_bounds__(256) void gemm_dt_mfma(
    const __hip_bfloat16* __restrict__ Xb, const __hip_bfloat16* __restrict__ Wb,
    const float* __restrict__ bias, __hip_bfloat16* __restrict__ DTb)
{
  __shared__ short As[3][128 * 32];
  __shared__ short Bs[3][64 * 32];
  const int tid  = threadIdx.x;
  const int lane = tid & 63;
  const int wid  = tid >> 6;        // 0..3
  const int wm   = wid >> 1, wn = wid & 1;

  // XCD swizzle: 1024 blocks, 8 XCDs; XCD r gets tiles [r*128, (r+1)*128)
  // = 8 contiguous row-panels x all 16 col-tiles (2MB Xb + 2MB Wb fits L2).
  const int bid  = blockIdx.x;
  const int tile = (bid & 7) * 128 + (bid >> 3);
  const int row0 = (tile >> 4) * 128;   // 64 row tiles
  const int col0 = (tile & 15) * 64;    // 16 col tiles

  const floatx4 zero = {0.f, 0.f, 0.f, 0.f};
  floatx4 acc[4][2];
#pragma unroll
  for (int i = 0; i < 4; ++i)
#pragma unroll
    for (int j = 0; j < 2; ++j) acc[i][j] = zero;

  // STAGE: 3 global_load_lds per thread (2 As + 1 Bs), 16B each
  auto STAGE = [&](int buf, int t) {
    const int k0 = t * 32;
#pragma unroll
    for (int q = 0; q < 2; ++q) {
      const int fe = q * 256 + tid;    // 0..511: As chunk id
      const int r  = fe >> 2;
      const int kk = (fe & 3) * 8;
      __builtin_amdgcn_global_load_lds(
          (const __attribute__((address_space(1))) void*)&Xb[(size_t)(row0 + r) * DM + k0 + kk],
          (__attribute__((address_space(3))) void*)&As[buf][fe * 8], 16, 0, 0);
    }
    const int rb  = tid >> 2;          // 0..63
    const int kkb = (tid & 3) * 8;
    __builtin_amdgcn_global_load_lds(
        (const __attribute__((address_space(1))) void*)&Wb[(size_t)(col0 + rb) * DM + k0 + kkb],
        (__attribute__((address_space(3))) void*)&Bs[buf][tid * 8], 16, 0, 0);
  };

  STAGE(0, 0);
  STAGE(1, 1);
  int cur = 0;
  for (int t = 0; t < NT; ++t) {
    if (t < NT - 1) asm volatile("s_waitcnt vmcnt(3)" ::: "memory");
    else            asm volatile("s_waitcnt vmcnt(0)" ::: "memory");
    __builtin_amdgcn_s_barrier();
    __builtin_amdgcn_sched_barrier(0);

    int c2 = cur + 2; if (c2 >= 3) c2 -= 3;
    if (t + 2 < NT) STAGE(c2, t + 2);

    short8 af[4], bfr[2];
#pragma unroll
    for (int i = 0; i < 4; ++i) {
      const int ar = wm * 64 + i * 16 + (lane & 15);
      af[i] = *(const short8*)&As[cur][ar * 32 + (lane >> 4) * 8];
    }
#pragma unroll
    for (int j = 0; j < 2; ++j) {
      const int br = wn * 32 + j * 16 + (lane & 15);
      bfr[j] = *(const short8*)&Bs[cur][br * 32 + (lane >> 4) * 8];
    }
#pragma unroll
    for (int i = 0; i < 4; ++i)
#pragma unroll
      for (int j = 0; j < 2; ++j)
        acc[i][j] = __builtin_amdgcn_mfma_f32_16x16x32_bf16(af[i], bfr[j], acc[i][j], 0, 0, 0);

    cur += 1; if (cur >= 3) cur -= 3;
  }

  // epilogue: bias + cheap softplus -> bf16. C/D: col=lane&15, row=(lane>>4)*4+r
  const int cl = lane & 15;
  const int rg = lane >> 4;
#pragma unroll
  for (int i = 0; i < 4; ++i) {
#pragma unroll
    for (int r = 0; r < 4; ++r) {
      const size_t row = (size_t)(row0 + wm * 64 + i * 16 + rg * 4 + r);
#pragma unroll
      for (int j = 0; j < 2; ++j) {
        const int col = col0 + wn * 32 + j * 16 + cl;
        const float v = acc[i][j][r] + bias[col];
        DTb[row * DM + col] = __float2bfloat16(softplus_fast(v));
      }
    }
  }
}

// ---- Kernel 3: per-chunk local scan (pass A), bf16 dt/x inputs ----
__global__ __launch_bounds__(256) void scan_partial_kernel(
    const __hip_bfloat16* __restrict__ DT, const __hip_bfloat16* __restrict__ X,
    const float* __restrict__ Bp, const float* __restrict__ A_log,
    float* __restrict__ PP, float* __restrict__ HP)
{
  const int d = blockIdx.x * 256 + threadIdx.x;
  const int c = blockIdx.y;
  const int b = blockIdx.z;
  float A[DS], h[DS];
  float sdt = 0.f;  // P[n] = exp(sdt * A[n]) at the end
  const float4* arow = (const float4*)&A_log[(size_t)d * DS];
#pragma unroll
  for (int m = 0; m < 4; ++m) {
    const float4 a4 = arow[m];
    A[m*4+0] = -__expf(a4.x); A[m*4+1] = -__expf(a4.y);
    A[m*4+2] = -__expf(a4.z); A[m*4+3] = -__expf(a4.w);
  }
#pragma unroll
  for (int n = 0; n < DS; ++n) h[n] = 0.f;

  const int l0 = c * LC;
  size_t idx = ((size_t)b * LL + l0) * DM + d;
  const float4* bv = (const float4*)&Bp[((size_t)b * LL + l0) * DS];

  float dtb[4], xb[4];
#pragma unroll
  for (int u = 0; u < 4; ++u) {
    dtb[u] = __bfloat162float(DT[idx + (size_t)u * DM]);
    xb[u]  = __bfloat162float(X[idx + (size_t)u * DM]);
  }

  for (int l = 0; l < LC; l += 4) {
    float dtn[4], xn[4];
    if (l + 4 < LC) {
#pragma unroll
      for (int u = 0; u < 4; ++u) {
        dtn[u] = __bfloat162float(DT[idx + (size_t)(u + 4) * DM]);
        xn[u]  = __bfloat162float(X[idx + (size_t)(u + 4) * DM]);
      }
    }
#pragma unroll
    for (int u = 0; u < 4; ++u) {
      const float dtv = dtb[u], xv = xb[u];
      const float dx = dtv * xv;
      sdt += dtv;
      const float4 b0 = bv[(l+u)*4+0], b1 = bv[(l+u)*4+1];
      const float4 b2 = bv[(l+u)*4+2], b3 = bv[(l+u)*4+3];
      const float bb[DS] = {b0.x,b0.y,b0.z,b0.w, b1.x,b1.y,b1.z,b1.w,
                            b2.x,b2.y,b2.z,b2.w, b3.x,b3.y,b3.z,b3.w};
#pragma unroll
      for (int n = 0; n < DS; ++n) {
        const float dA = __expf(dtv * A[n]);
        h[n] = fmaf(dA, h[n], dx * bb[n]);
      }
    }
    idx += (size_t)4 * DM;
#pragma unroll
    for (int u = 0; u < 4; ++u) { dtb[u] = dtn[u]; xb[u] = xn[u]; }
  }
  const size_t o = (((size_t)b * NC + c) * DM + d) * DS;
  float4* pp = (float4*)&PP[o];
  float4* hp = (float4*)&HP[o];
#pragma unroll
  for (int m = 0; m < 4; ++m) {
    pp[m] = make_float4(__expf(sdt * A[m*4+0]), __expf(sdt * A[m*4+1]),
                        __expf(sdt * A[m*4+2]), __expf(sdt * A[m*4+3]));
    hp[m] = make_float4(h[m*4+0], h[m*4+1], h[m*4+2], h[m*4+3]);
  }
}

// ---- Kernel 4: combine chunk prefixes (sequential over NC) ----
__global__ __launch_bounds__(256) void combine_kernel(
    float* __restrict__ PP, const float* __restrict__ HP)
{
  const int idx = blockIdx.x * 256 + threadIdx.x;  // over B*DM*DS = 65536
  const int b  = idx >> 14;
  const int dn = idx & 16383;
  float h = 0.f;
#pragma unroll 4
  for (int c = 0; c < NC; ++c) {
    const size_t o = (((size_t)b * NC + c) << 14) + dn;
    const float p  = PP[o];
    const float hp = HP[o];
    PP[o] = h;              // Hin for chunk c
    h = fmaf(p, h, hp);
  }
}

// ---- Kernel 5: final scan + output (pass B), bf16 dt/x inputs ----
__global__ __launch_bounds__(256) void scan_final_kernel(
    const __hip_bfloat16* __restrict__ DT, const __hip_bfloat16* __restrict__ X,
    const float* __restrict__ Bp, const float* __restrict__ Cp,
    const float* __restrict__ A_log, const float* __restrict__ Dvec,
    const float* __restrict__ Hin, float* __restrict__ Y)
{
  const int d = blockIdx.x * 256 + threadIdx.x;
  const int c = blockIdx.y;
  const int b = blockIdx.z;
  float A[DS], h[DS];
  const float4* arow = (const float4*)&A_log[(size_t)d * DS];
  const size_t o = (((size_t)b * NC + c) * DM + d) * DS;
  const float4* hin = (const float4*)&Hin[o];
#pragma unroll
  for (int m = 0; m < 4; ++m) {
    const float4 a4 = arow[m];
    A[m*4+0] = -__expf(a4.x); A[m*4+1] = -__expf(a4.y);
    A[m*4+2] = -__expf(a4.z); A[m*4+3] = -__expf(a4.w);
    const float4 h4 = hin[m];
    h[m*4+0] = h4.x; h[m*4+1] = h4.y; h[m*4+2] = h4.z; h[m*4+3] = h4.w;
  }
  const float Dd = Dvec[d];
  const int l0 = c * LC;
  size_t idx = ((size_t)b * LL + l0) * DM + d;
  const float4* bv = (const float4*)&Bp[((size_t)b * LL + l0) * DS];
  const float4* cv = (const float4*)&Cp[((size_t)b * LL + l0) * DS];

  float dtb[4], xb[4];
#pragma unroll
  for (int u = 0; u < 4; ++u) {
    dtb[u] = __bfloat162float(DT[idx + (size_t)u * DM]);
    xb[u]  = __bfloat162float(X[idx + (size_t)u * DM]);
  }

  for (int l = 0; l < LC; l += 4) {
    float dtn[4], xn[4];
    if (l + 4 < LC) {
#pragma unroll
      for (int u = 0; u < 4; ++u) {
        dtn[u] = __bfloat162float(DT[idx + (size_t)(u + 4) * DM]);
        xn[u]  = __bfloat162float(X[idx + (size_t)(u + 4) * DM]);
      }
    }
#pragma unroll
    for (int u = 0; u < 4; ++u) {
      const float dtv = dtb[u], xv = xb[u];
      const float dx = dtv * xv;
      const float4 b0 = bv[(l+u)*4+0], b1 = bv[(l+u)*4+1];
      const float4 b2 = bv[(l+u)*4+2], b3 = bv[(l+u)*4+3];
      const float bb[DS] = {b0.x,b0.y,b0.z,b0.w, b1.x,b1.y,b1.z,b1.w,
                            b2.x,b2.y,b2.z,b2.w, b3.x,b3.y,b3.z,b3.w};
      const float4 c0 = cv[(l+u)*4+0], c1 = cv[(l+u)*4+1];
      const float4 c2 = cv[(l+u)*4+2], c3 = cv[(l+u)*4+3];
      const float cc[DS] = {c0.x,c0.y,c0.z,c0.w, c1.x,c1.y,c1.z,c1.w,
                            c2.x,c2.y,c2.z,c2.w, c3.x,c3.y,c3.z,c3.w};
      float y = 0.f;
#pragma unroll
      for (int n = 0; n < DS; ++n) {
        const float dA = __expf(dtv * A[n]);
        h[n] = fmaf(dA, h[n], dx * bb[n]);
        y = fmaf(h[n], cc[n], y);
      }
      Y[idx + (size_t)u * DM] = fmaf(Dd, xv, y);
    }
    idx += (size_t)4 * DM;
#pragma unroll
    for (int u = 0; u < 4; ++u) { dtb[u] = dtn[u]; xb[u] = xn[u]; }
  }
}

// ---- launch ----
// Workspace (float slots):
//   DTb : MT*DM bf16            = 4194304 slots
//   BP  : MT*DS                 =  131072
//   CP  : MT*DS                 =  131072
//   Xb  : MT*DM bf16            = 4194304 slots
//   U   : union { Wb (DM*DM bf16, dead after GEMM), PP } = 4194304
//   HP  : BB*NC*DM*DS           = 4194304
// total = 16976128 floats = 67,904,512 bytes.
extern "C" void kernel_launch(void* const* d_in, const int* in_sizes, int n_in,
                              void* d_out, int out_size, void* d_ws, size_t ws_size,
                              hipStream_t stream)
{
  const float* x     = (const float*)d_in[0];
  const float* W_dt  = (const float*)d_in[1];
  const float* b_dt  = (const float*)d_in[2];
  const float* W_B   = (const float*)d_in[3];
  const float* W_C   = (const float*)d_in[4];
  const float* A_log = (const float*)d_in[5];
  const float* Dv    = (const float*)d_in[6];
  float* Y  = (float*)d_out;
  float* ws = (float*)d_ws;

  __hip_bfloat16* DTb = (__hip_bfloat16*)ws;
  float* BP = ws + (size_t)MT * DM / 2;
  float* CP = BP + (size_t)MT * DS;
  __hip_bfloat16* Xb = (__hip_bfloat16*)(CP + (size_t)MT * DS);
  float* U  = CP + (size_t)MT * DS + (size_t)MT * DM / 2;
  __hip_bfloat16* Wb = (__hip_bfloat16*)U;
  float* PP = U;
  float* HP = U + (size_t)BB * NC * DM * DS;

  prep_kernel<<<1536, 256, 0, stream>>>(x, W_dt, W_B, W_C, BP, CP, Xb, Wb);
  gemm_dt_mfma<<<1024, 256, 0, stream>>>(Xb, Wb, b_dt, DTb);
  scan_partial_kernel<<<dim3(DM / 256, NC, BB), 256, 0, stream>>>(DTb, Xb, BP, A_log, PP, HP);
  combine_kernel<<<(BB * DM * DS) / 256, 256, 0, stream>>>(PP, HP);
  scan_final_kernel<<<dim3(DM / 256, NC, BB), 256, 0, stream>>>(DTb, Xb, BP, CP, A_log, Dv, PP, Y);
}

// Round 5
// 143.405 us; speedup vs baseline: 2.7100x; 1.1109x over previous
//
#include <hip/hip_runtime.h>
#include <hip/hip_bf16.h>
#include <math.h>

// Problem constants
#define DM 1024    // d_model
#define DS 16      // d_state
#define BB 4       // batch
#define LL 2048    // seq len
#define LC 32      // scan chunk length
#define NC (LL/LC) // 64 chunks
#define MT 8192    // B*L tokens
#define NT 32      // GEMM k-steps (DM/32)
#define NCT 17     // GEMM col tiles (16 dt + 1 B/C)

typedef __attribute__((ext_vector_type(8))) short short8;
typedef __attribute__((ext_vector_type(4))) float floatx4;

__device__ __forceinline__ float softplus_fast(float v) {
  // max(v,0) + log(1+exp(-|v|)); abs err ~1e-6, negligible vs bf16 storage
  return fmaxf(v, 0.f) + __logf(1.f + __expf(-fabsf(v)));
}

// ---- Kernel 1: pure streaming convert: X->Xb, [W_dt;W_B;W_C;0]->Wx (bf16) ----
// Unit = 8 elements. Ranges: X | W_dt | WB | WC | zero-pad rows 1056..1087.
__global__ __launch_bounds__(256) void convert_kernel(
    const float* __restrict__ X, const float* __restrict__ W_dt,
    const float* __restrict__ WB, const float* __restrict__ WC,
    __hip_bfloat16* __restrict__ Xb, __hip_bfloat16* __restrict__ Wx)
{
  const size_t i  = (size_t)blockIdx.x * 256 + threadIdx.x;
  const size_t NX = (size_t)MT * DM / 8;   // 1048576
  const size_t NW = (size_t)DM * DM / 8;   //  131072
  const size_t NB = (size_t)DS * DM / 8;   //    2048
  const float* src;
  __hip_bfloat16* dst;
  size_t u;
  if (i < NX)                { src = X;    dst = Xb;                        u = i; }
  else if (i < NX + NW)      { src = W_dt; dst = Wx;                        u = i - NX; }
  else if (i < NX + NW + NB) { src = WB;   dst = Wx + (size_t)1024 * DM;    u = i - NX - NW; }
  else if (i < NX + NW + 2 * NB) { src = WC; dst = Wx + (size_t)1040 * DM;  u = i - NX - NW - NB; }
  else {
    const size_t z = i - NX - NW - 2 * NB;   // 0..4095 -> pad rows 1056..1087
    const short8 zz = {0, 0, 0, 0, 0, 0, 0, 0};
    *(short8*)&Wx[(size_t)1056 * DM + z * 8] = zz;
    return;
  }
  const float4 a = *(const float4*)&src[u * 8];
  const float4 b = *(const float4*)&src[u * 8 + 4];
  union { short8 v; __hip_bfloat16 h[8]; } o;
  o.h[0] = __float2bfloat16(a.x); o.h[1] = __float2bfloat16(a.y);
  o.h[2] = __float2bfloat16(a.z); o.h[3] = __float2bfloat16(a.w);
  o.h[4] = __float2bfloat16(b.x); o.h[5] = __float2bfloat16(b.y);
  o.h[6] = __float2bfloat16(b.z); o.h[7] = __float2bfloat16(b.w);
  *(short8*)&dst[u * 8] = o.v;
}

// ---- Kernel 2: [DT | Bp | Cp] = Xb @ Wx^T (+bias/softplus on dt cols) ----
// BM=128, BN=64, BK=32; 64x17=1088 blocks, 4 waves (2x2), 4x2 frags/wave.
// 3 LDS buffers, 2-deep prefetch, counted vmcnt(3). XCD-swizzled tiles.
__global__ __launch_bounds__(256) void gemm_dt_mfma(
    const __hip_bfloat16* __restrict__ Xb, const __hip_bfloat16* __restrict__ Wx,
    const float* __restrict__ bias, __hip_bfloat16* __restrict__ DTb,
    float* __restrict__ BP, float* __restrict__ CP)
{
  __shared__ short As[3][128 * 32];
  __shared__ short Bs[3][64 * 32];
  const int tid  = threadIdx.x;
  const int lane = tid & 63;
  const int wid  = tid >> 6;        // 0..3
  const int wm   = wid >> 1, wn = wid & 1;

  // XCD swizzle: 1088 blocks = 8 XCDs x 136. Each XCD: 8 row-panels x 17 col
  // tiles -> 2MB Xb panel + 2.2MB Wx fits its 4MB L2.
  const int bid  = blockIdx.x;
  const int tile = (bid & 7) * 136 + (bid >> 3);
  const int row0 = (tile / NCT) * 128;
  const int col0 = (tile % NCT) * 64;

  const floatx4 zero = {0.f, 0.f, 0.f, 0.f};
  floatx4 acc[4][2];
#pragma unroll
  for (int i = 0; i < 4; ++i)
#pragma unroll
    for (int j = 0; j < 2; ++j) acc[i][j] = zero;

  // STAGE: 3 global_load_lds per thread (2 As + 1 Bs), 16B each
  auto STAGE = [&](int buf, int t) {
    const int k0 = t * 32;
#pragma unroll
    for (int q = 0; q < 2; ++q) {
      const int fe = q * 256 + tid;    // 0..511: As chunk id
      const int r  = fe >> 2;
      const int kk = (fe & 3) * 8;
      __builtin_amdgcn_global_load_lds(
          (const __attribute__((address_space(1))) void*)&Xb[(size_t)(row0 + r) * DM + k0 + kk],
          (__attribute__((address_space(3))) void*)&As[buf][fe * 8], 16, 0, 0);
    }
    const int rb  = tid >> 2;          // 0..63
    const int kkb = (tid & 3) * 8;
    __builtin_amdgcn_global_load_lds(
        (const __attribute__((address_space(1))) void*)&Wx[(size_t)(col0 + rb) * DM + k0 + kkb],
        (__attribute__((address_space(3))) void*)&Bs[buf][tid * 8], 16, 0, 0);
  };

  STAGE(0, 0);
  STAGE(1, 1);
  int cur = 0;
  for (int t = 0; t < NT; ++t) {
    if (t < NT - 1) asm volatile("s_waitcnt vmcnt(3)" ::: "memory");
    else            asm volatile("s_waitcnt vmcnt(0)" ::: "memory");
    __builtin_amdgcn_s_barrier();
    __builtin_amdgcn_sched_barrier(0);

    int c2 = cur + 2; if (c2 >= 3) c2 -= 3;
    if (t + 2 < NT) STAGE(c2, t + 2);

    short8 af[4], bfr[2];
#pragma unroll
    for (int i = 0; i < 4; ++i) {
      const int ar = wm * 64 + i * 16 + (lane & 15);
      af[i] = *(const short8*)&As[cur][ar * 32 + (lane >> 4) * 8];
    }
#pragma unroll
    for (int j = 0; j < 2; ++j) {
      const int br = wn * 32 + j * 16 + (lane & 15);
      bfr[j] = *(const short8*)&Bs[cur][br * 32 + (lane >> 4) * 8];
    }
#pragma unroll
    for (int i = 0; i < 4; ++i)
#pragma unroll
      for (int j = 0; j < 2; ++j)
        acc[i][j] = __builtin_amdgcn_mfma_f32_16x16x32_bf16(af[i], bfr[j], acc[i][j], 0, 0, 0);

    cur += 1; if (cur >= 3) cur -= 3;
  }

  // epilogue. C/D layout: col=lane&15, row=(lane>>4)*4+r
  const int cl = lane & 15;
  const int rg = lane >> 4;
  if (col0 < 1024) {
    // dt path: bias + softplus -> bf16
#pragma unroll
    for (int i = 0; i < 4; ++i) {
#pragma unroll
      for (int r = 0; r < 4; ++r) {
        const size_t row = (size_t)(row0 + wm * 64 + i * 16 + rg * 4 + r);
#pragma unroll
        for (int j = 0; j < 2; ++j) {
          const int col = col0 + wn * 32 + j * 16 + cl;
          const float v = acc[i][j][r] + bias[col];
          DTb[row * DM + col] = __float2bfloat16(softplus_fast(v));
        }
      }
    }
  } else if (wn == 0) {
    // B/C tile: wn==0 j==0 -> Bp (cols 1024..1039), j==1 -> Cp (1040..1055)
#pragma unroll
    for (int i = 0; i < 4; ++i) {
#pragma unroll
      for (int r = 0; r < 4; ++r) {
        const size_t row = (size_t)(row0 + wm * 64 + i * 16 + rg * 4 + r);
        BP[row * DS + cl] = acc[i][0][r];
        CP[row * DS + cl] = acc[i][1][r];
      }
    }
  }
}

// ---- Kernel 3: per-chunk local scan (pass A), bf16 dt/x inputs ----
__global__ __launch_bounds__(256) void scan_partial_kernel(
    const __hip_bfloat16* __restrict__ DT, const __hip_bfloat16* __restrict__ X,
    const float* __restrict__ Bp, const float* __restrict__ A_log,
    float* __restrict__ PP, float* __restrict__ HP)
{
  const int d = blockIdx.x * 256 + threadIdx.x;
  const int c = blockIdx.y;
  const int b = blockIdx.z;
  float A[DS], h[DS];
  float sdt = 0.f;  // P[n] = exp(sdt * A[n]) at the end
  const float4* arow = (const float4*)&A_log[(size_t)d * DS];
#pragma unroll
  for (int m = 0; m < 4; ++m) {
    const float4 a4 = arow[m];
    A[m*4+0] = -__expf(a4.x); A[m*4+1] = -__expf(a4.y);
    A[m*4+2] = -__expf(a4.z); A[m*4+3] = -__expf(a4.w);
  }
#pragma unroll
  for (int n = 0; n < DS; ++n) h[n] = 0.f;

  const int l0 = c * LC;
  size_t idx = ((size_t)b * LL + l0) * DM + d;
  const float4* bv = (const float4*)&Bp[((size_t)b * LL + l0) * DS];

  float dtb[4], xb[4];
#pragma unroll
  for (int u = 0; u < 4; ++u) {
    dtb[u] = __bfloat162float(DT[idx + (size_t)u * DM]);
    xb[u]  = __bfloat162float(X[idx + (size_t)u * DM]);
  }

  for (int l = 0; l < LC; l += 4) {
    float dtn[4], xn[4];
    if (l + 4 < LC) {
#pragma unroll
      for (int u = 0; u < 4; ++u) {
        dtn[u] = __bfloat162float(DT[idx + (size_t)(u + 4) * DM]);
        xn[u]  = __bfloat162float(X[idx + (size_t)(u + 4) * DM]);
      }
    }
#pragma unroll
    for (int u = 0; u < 4; ++u) {
      const float dtv = dtb[u], xv = xb[u];
      const float dx = dtv * xv;
      sdt += dtv;
      const float4 b0 = bv[(l+u)*4+0], b1 = bv[(l+u)*4+1];
      const float4 b2 = bv[(l+u)*4+2], b3 = bv[(l+u)*4+3];
      const float bb[DS] = {b0.x,b0.y,b0.z,b0.w, b1.x,b1.y,b1.z,b1.w,
                            b2.x,b2.y,b2.z,b2.w, b3.x,b3.y,b3.z,b3.w};
#pragma unroll
      for (int n = 0; n < DS; ++n) {
        const float dA = __expf(dtv * A[n]);
        h[n] = fmaf(dA, h[n], dx * bb[n]);
      }
    }
    idx += (size_t)4 * DM;
#pragma unroll
    for (int u = 0; u < 4; ++u) { dtb[u] = dtn[u]; xb[u] = xn[u]; }
  }
  const size_t o = (((size_t)b * NC + c) * DM + d) * DS;
  float4* pp = (float4*)&PP[o];
  float4* hp = (float4*)&HP[o];
#pragma unroll
  for (int m = 0; m < 4; ++m) {
    pp[m] = make_float4(__expf(sdt * A[m*4+0]), __expf(sdt * A[m*4+1]),
                        __expf(sdt * A[m*4+2]), __expf(sdt * A[m*4+3]));
    hp[m] = make_float4(h[m*4+0], h[m*4+1], h[m*4+2], h[m*4+3]);
  }
}

// ---- Kernel 4: combine chunk prefixes (sequential over NC) ----
__global__ __launch_bounds__(256) void combine_kernel(
    float* __restrict__ PP, const float* __restrict__ HP)
{
  const int idx = blockIdx.x * 256 + threadIdx.x;  // over B*DM*DS = 65536
  const int b  = idx >> 14;
  const int dn = idx & 16383;
  float h = 0.f;
#pragma unroll 4
  for (int c = 0; c < NC; ++c) {
    const size_t o = (((size_t)b * NC + c) << 14) + dn;
    const float p  = PP[o];
    const float hp = HP[o];
    PP[o] = h;              // Hin for chunk c
    h = fmaf(p, h, hp);
  }
}

// ---- Kernel 5: final scan + output (pass B), bf16 dt/x inputs ----
__global__ __launch_bounds__(256) void scan_final_kernel(
    const __hip_bfloat16* __restrict__ DT, const __hip_bfloat16* __restrict__ X,
    const float* __restrict__ Bp, const float* __restrict__ Cp,
    const float* __restrict__ A_log, const float* __restrict__ Dvec,
    const float* __restrict__ Hin, float* __restrict__ Y)
{
  const int d = blockIdx.x * 256 + threadIdx.x;
  const int c = blockIdx.y;
  const int b = blockIdx.z;
  float A[DS], h[DS];
  const float4* arow = (const float4*)&A_log[(size_t)d * DS];
  const size_t o = (((size_t)b * NC + c) * DM + d) * DS;
  const float4* hin = (const float4*)&Hin[o];
#pragma unroll
  for (int m = 0; m < 4; ++m) {
    const float4 a4 = arow[m];
    A[m*4+0] = -__expf(a4.x); A[m*4+1] = -__expf(a4.y);
    A[m*4+2] = -__expf(a4.z); A[m*4+3] = -__expf(a4.w);
    const float4 h4 = hin[m];
    h[m*4+0] = h4.x; h[m*4+1] = h4.y; h[m*4+2] = h4.z; h[m*4+3] = h4.w;
  }
  const float Dd = Dvec[d];
  const int l0 = c * LC;
  size_t idx = ((size_t)b * LL + l0) * DM + d;
  const float4* bv = (const float4*)&Bp[((size_t)b * LL + l0) * DS];
  const float4* cv = (const float4*)&Cp[((size_t)b * LL + l0) * DS];

  float dtb[4], xb[4];
#pragma unroll
  for (int u = 0; u < 4; ++u) {
    dtb[u] = __bfloat162float(DT[idx + (size_t)u * DM]);
    xb[u]  = __bfloat162float(X[idx + (size_t)u * DM]);
  }

  for (int l = 0; l < LC; l += 4) {
    float dtn[4], xn[4];
    if (l + 4 < LC) {
#pragma unroll
      for (int u = 0; u < 4; ++u) {
        dtn[u] = __bfloat162float(DT[idx + (size_t)(u + 4) * DM]);
        xn[u]  = __bfloat162float(X[idx + (size_t)(u + 4) * DM]);
      }
    }
#pragma unroll
    for (int u = 0; u < 4; ++u) {
      const float dtv = dtb[u], xv = xb[u];
      const float dx = dtv * xv;
      const float4 b0 = bv[(l+u)*4+0], b1 = bv[(l+u)*4+1];
      const float4 b2 = bv[(l+u)*4+2], b3 = bv[(l+u)*4+3];
      const float bb[DS] = {b0.x,b0.y,b0.z,b0.w, b1.x,b1.y,b1.z,b1.w,
                            b2.x,b2.y,b2.z,b2.w, b3.x,b3.y,b3.z,b3.w};
      const float4 c0 = cv[(l+u)*4+0], c1 = cv[(l+u)*4+1];
      const float4 c2 = cv[(l+u)*4+2], c3 = cv[(l+u)*4+3];
      const float cc[DS] = {c0.x,c0.y,c0.z,c0.w, c1.x,c1.y,c1.z,c1.w,
                            c2.x,c2.y,c2.z,c2.w, c3.x,c3.y,c3.z,c3.w};
      float y = 0.f;
#pragma unroll
      for (int n = 0; n < DS; ++n) {
        const float dA = __expf(dtv * A[n]);
        h[n] = fmaf(dA, h[n], dx * bb[n]);
        y = fmaf(h[n], cc[n], y);
      }
      Y[idx + (size_t)u * DM] = fmaf(Dd, xv, y);
    }
    idx += (size_t)4 * DM;
#pragma unroll
    for (int u = 0; u < 4; ++u) { dtb[u] = dtn[u]; xb[u] = xn[u]; }
  }
}

// ---- launch ----
// Workspace (float slots):
//   DTb : MT*DM bf16            = 4194304 slots
//   BP  : MT*DS                 =  131072
//   CP  : MT*DS                 =  131072
//   Xb  : MT*DM bf16            = 4194304 slots
//   U   : union { Wx (1088*1024 bf16 = 557056 slots, dead after GEMM),
//                 PP (4194304, live after GEMM) } = 4194304
//   HP  : BB*NC*DM*DS           = 4194304
// total = 17039360 floats = 68,157,440 bytes.
extern "C" void kernel_launch(void* const* d_in, const int* in_sizes, int n_in,
                              void* d_out, int out_size, void* d_ws, size_t ws_size,
                              hipStream_t stream)
{
  const float* x     = (const float*)d_in[0];
  const float* W_dt  = (const float*)d_in[1];
  const float* b_dt  = (const float*)d_in[2];
  const float* W_B   = (const float*)d_in[3];
  const float* W_C   = (const float*)d_in[4];
  const float* A_log = (const float*)d_in[5];
  const float* Dv    = (const float*)d_in[6];
  float* Y  = (float*)d_out;
  float* ws = (float*)d_ws;

  __hip_bfloat16* DTb = (__hip_bfloat16*)ws;
  float* BP = ws + (size_t)MT * DM / 2;
  float* CP = BP + (size_t)MT * DS;
  __hip_bfloat16* Xb = (__hip_bfloat16*)(CP + (size_t)MT * DS);
  float* U  = CP + (size_t)MT * DS + (size_t)MT * DM / 2;
  __hip_bfloat16* Wx = (__hip_bfloat16*)U;
  float* PP = U;
  float* HP = U + (size_t)BB * NC * DM * DS;

  convert_kernel<<<4640, 256, 0, stream>>>(x, W_dt, W_B, W_C, Xb, Wx);
  gemm_dt_mfma<<<1088, 256, 0, stream>>>(Xb, Wx, b_dt, DTb, BP, CP);
  scan_partial_kernel<<<dim3(DM / 256, NC, BB), 256, 0, stream>>>(DTb, Xb, BP, A_log, PP, HP);
  combine_kernel<<<(BB * DM * DS) / 256, 256, 0, stream>>>(PP, HP);
  scan_final_kernel<<<dim3(DM / 256, NC, BB), 256, 0, stream>>>(DTb, Xb, BP, CP, A_log, Dv, PP, Y);
}